// Round 8
// baseline (190.136 us; speedup 1.0000x reference)
//
#include <hip/hip_runtime.h>
#include <math.h>

#define T_IN 64
#define NPIX 16384
#define MAX_ITER 10
#define NSLOT 43
#define MAGIC 0x13579BDFu

typedef _Float16 half8_t __attribute__((ext_vector_type(8)));
typedef __fp16   fp16x2  __attribute__((ext_vector_type(2)));
typedef float    f32x4   __attribute__((ext_vector_type(4)));
typedef int      i32x4   __attribute__((ext_vector_type(4)));

union H8 { half8_t v; fp16x2 h2[4]; i32x4 i4; };

__device__ __forceinline__ float rcp_fast(float x) { return __builtin_amdgcn_rcpf(x); }

// ---------------------------------------------------------------- all -------
// Single dispatch, grid 256 (=CU count; 2-blocks/CU resource headroom so all
// blocks are guaranteed co-resident -> software grid barrier is deadlock-free).
// Phase A: local setup (aif_os/tsh), dcreg, block C_dc/C_nn partials -> global
// partials[blk] + release flag. B-build/hoist overlaps barrier skew. Spin on
// flags (agent-scope acquire), reduce partials, then the R7 main loop.
__global__ __launch_bounds__(256, 2) void k_all(
        const float* __restrict__ ctc,  const float* __restrict__ aif,
        const float* __restrict__ timev,const float* __restrict__ lam,
        const float* __restrict__ eta,  unsigned int* __restrict__ flags,
        f32x4* __restrict__ partials,   float* __restrict__ out) {
    __shared__ i32x4 Bs[NSLOT * 64];   // 43 KB
    __shared__ float tshs[512];        // 2 KB
    __shared__ float aifos[512];       // 2 KB
    __shared__ float a_s[64], t_s[64];
    __shared__ f32x4 red[4];

    const int tid  = threadIdx.x;
    const int lane = tid & 63;
    const int wid  = tid >> 6;
    const int q = lane >> 4, n = lane & 15;
    const int pixbase = blockIdx.x * 64 + wid * 16;
    const int mypix   = pixbase + n;

    // ---- phase A: local setup ----
    if (tid < 64) { a_s[tid] = aif[tid]; t_s[tid] = timev[tid]; }
    float A  = eta[mypix];
    float K  = eta[NPIX + mypix];
    float T0 = eta[2*NPIX + mypix];
    const float pA = A, pK = K, pT = T0;
    __syncthreads();
    {
        float m5a = 0.2f * (a_s[0]+a_s[1]+a_s[2]+a_s[3]+a_s[4]);
        float t16;
        {   // t_os[16]: x = (16-3.5)/8 = 1.5625
            float xx = 1.5625f; int i0 = (int)xx; float f = xx - (float)i0;
            t16 = t_s[i0]*(1.0f-f) + t_s[i0+1]*f;
        }
        #pragma unroll
        for (int rep = 0; rep < 2; ++rep) {
            int i = tid + 256*rep;
            float x = ((float)i - 3.5f) * 0.125f;
            float ao, to;
            if (x <= 0.0f)       { ao = a_s[0]  - m5a; to = t_s[0];  }
            else if (x >= 63.0f) { ao = a_s[63] - m5a; to = t_s[63]; }
            else {
                int i0 = (int)x; float f = x - (float)i0;
                ao = (a_s[i0]-m5a)*(1.0f-f) + (a_s[i0+1]-m5a)*f;
                to = t_s[i0]*(1.0f-f) + t_s[i0+1]*f;
            }
            aifos[i] = ao;
            tshs[i]  = to - t16;
        }
    }

    // ctc_dc in C-layout registers: dcreg[nt][reg] = dc[p=q*4+reg][d=nt*16+n]
    float dcreg[4][4];
    #pragma unroll
    for (int reg = 0; reg < 4; ++reg) {
        const float* cp = ctc + (pixbase + q*4 + reg) * T_IN;
        float m5 = 0.2f * (cp[0]+cp[1]+cp[2]+cp[3]+cp[4]);
        #pragma unroll
        for (int nt = 0; nt < 4; ++nt) {
            int d = nt*16 + n;
            float cc = cp[d] - m5;
            float cm = cp[(d > 0) ? d-1 : 0] - m5;
            dcreg[nt][reg] = (d == 0) ? cc : (0.4375f*cm + 0.5625f*cc);
        }
    }

    // block partials: C_dc = sum dcreg^2 (each (px,d) once across the wave);
    // C_nn: each pixel appears on 4 lanes (q=0..3) -> sum/4.
    {
        float vs = 0.f;
        #pragma unroll
        for (int nt = 0; nt < 4; ++nt)
            #pragma unroll
            for (int r2 = 0; r2 < 4; ++r2) vs += dcreg[nt][r2]*dcreg[nt][r2];
        f32x4 pv = (f32x4){vs, 0.25f*A*A, 0.25f*K*K, 0.25f*T0*T0};
        #pragma unroll
        for (int m = 1; m < 64; m <<= 1) {
            pv.x += __shfl_xor(pv.x, m); pv.y += __shfl_xor(pv.y, m);
            pv.z += __shfl_xor(pv.z, m); pv.w += __shfl_xor(pv.w, m);
        }
        if (lane == 0) red[wid] = pv;
    }
    __syncthreads();
    if (tid == 0) {
        f32x4 s = red[0] + red[1] + red[2] + red[3];
        partials[blockIdx.x] = s;
        __threadfence();
        __hip_atomic_store(&flags[blockIdx.x], MAGIC, __ATOMIC_RELEASE,
                           __HIP_MEMORY_SCOPE_AGENT);
    }

    // ---- build B tiles in LDS (overlaps barrier skew), RTN ----
    for (int idx = tid; idx < NSLOT * 64; idx += 256) {
        int slot = idx >> 6, l = idx & 63;
        int kt, nt;
        if (slot < 20)      { kt = slot >> 2; nt = slot & 3; }
        else if (slot < 32) { int s = slot - 20; int d3 = s / 3; kt = 5 + d3; nt = 1 + (s - 3*d3); }
        else if (slot < 40) { int s = slot - 32; kt = 9 + (s >> 1); nt = 2 + (s & 1); }
        else                { kt = 13 + (slot - 40); nt = 3; }
        int kbase = 32*kt + 8*(l >> 4);
        int m = 16 + 8 * (16*nt + (l & 15));   // m_d = 16+8d
        H8 bh;
        #pragma unroll
        for (int jj = 0; jj < 4; ++jj) {
            float v[2];
            #pragma unroll
            for (int h = 0; h < 2; ++h) {
                int k  = kbase + 2*jj + h;
                int ai = m - k;
                float s2 = 1.0f / (1.0f + __expf(-500.0f * tshs[k]));
                v[h] = (ai >= 0 && ai < 512) ? s2 * aifos[ai] * 0.125f : 0.0f;
            }
            bh.h2[jj] = (fp16x2){(__fp16)v[0], (__fp16)v[1]};   // RTN
        }
        Bs[idx] = bh.i4;
    }
    __syncthreads();

    // ---- hoist B into registers (iteration-invariant) ----
    i32x4 Breg[NSLOT];
    #pragma unroll
    for (int s = 0; s < NSLOT; ++s) Breg[s] = Bs[s*64 + lane];

    // ---- grid barrier: thread t watches flags[t] ----
    while (__hip_atomic_load(&flags[tid], __ATOMIC_ACQUIRE,
                             __HIP_MEMORY_SCOPE_AGENT) != MAGIC)
        __builtin_amdgcn_s_sleep(2);
    __syncthreads();

    // ---- reduce the 256 partials (4 per lane, then wave shuffle) ----
    f32x4 tot = partials[lane] + partials[64+lane] + partials[128+lane]
              + partials[192+lane];
    #pragma unroll
    for (int m = 1; m < 64; m <<= 1) {
        tot.x += __shfl_xor(tot.x, m); tot.y += __shfl_xor(tot.y, m);
        tot.z += __shfl_xor(tot.z, m); tot.w += __shfl_xor(tot.w, m);
    }
    float spl;
    {
        float xl = lam[0];
        spl = (xl > 0.0f) ? (xl + log1pf(__expf(-xl))) : log1pf(__expf(xl));
    }
    const float cdc2 = 2.0f / tot.x;
    const float rgA  = 2.0f * spl / tot.y;
    const float rgK  = 2.0f * spl / tot.z;
    const float rgT  = 2.0f * spl / tot.w;

    constexpr int NTMIN[16] = {0,0,0,0,0,1,1,1,1,2,2,2,2,3,3,3};
    constexpr int TOFS[16]  = {0,4,8,12,16,20,23,26,29,32,34,36,38,40,41,42};

    #pragma unroll 1
    for (int it = 0; it < MAX_ITER; ++it) {
        f32x4 acc[3][4];
        #pragma unroll
        for (int f = 0; f < 3; ++f)
            #pragma unroll
            for (int t = 0; t < 4; ++t)
                acc[f][t] = (f32x4){0.f, 0.f, 0.f, 0.f};

        float nK = -K;
        float r  = __expf(0.125f * K);     // x ratio per t-step
        #pragma unroll
        for (int kt = 0; kt < 16; ++kt) {
            f32x4 tv0 = *(const f32x4*)&tshs[32*kt + 8*q];
            f32x4 tv1 = *(const f32x4*)&tshs[32*kt + 8*q + 4];
            float d1[8];
            d1[0]=T0-tv0[0]; d1[1]=T0-tv0[1]; d1[2]=T0-tv0[2]; d1[3]=T0-tv0[3];
            d1[4]=T0-tv1[0]; d1[5]=T0-tv1[1]; d1[6]=T0-tv1[2]; d1[7]=T0-tv1[3];
            float x[8];
            if (kt == 0 || kt == 15) {
                bool edge = (kt == 0) ? (q == 0) : (q == 3);  // flat tsh samples
                if (edge) {
                    #pragma unroll
                    for (int j = 0; j < 8; ++j) x[j] = __expf(nK * d1[j]);
                } else {
                    x[0] = __expf(nK * d1[0]);
                    #pragma unroll
                    for (int j = 1; j < 8; ++j) x[j] = x[j-1] * r;
                }
            } else {
                x[0] = __expf(nK * d1[0]);
                #pragma unroll
                for (int j = 1; j < 8; ++j) x[j] = x[j-1] * r;
            }
            H8 F0h, F1h, F2h;
            #pragma unroll
            for (int jj = 0; jj < 4; ++jj) {
                float s1a = rcp_fast(1.0f + x[2*jj]);
                float s1b = rcp_fast(1.0f + x[2*jj+1]);
                fp16x2 sh  = (fp16x2){(__fp16)s1a, (__fp16)s1b};          // RTN
                fp16x2 d1h = __builtin_amdgcn_cvt_pkrtz(d1[2*jj], d1[2*jj+1]);
                fp16x2 eh  = sh - sh*sh;                                  // v_pk f16
                F0h.h2[jj] = sh;
                F1h.h2[jj] = eh * d1h;
                F2h.h2[jj] = eh;
            }
            #pragma unroll
            for (int nt = NTMIN[kt]; nt < 4; ++nt) {
                int slot = TOFS[kt] + nt - NTMIN[kt];
                H8 bh; bh.i4 = Breg[slot];
                acc[0][nt] = __builtin_amdgcn_mfma_f32_16x16x32_f16(F0h.v, bh.v, acc[0][nt], 0, 0, 0);
                acc[1][nt] = __builtin_amdgcn_mfma_f32_16x16x32_f16(F1h.v, bh.v, acc[1][nt], 0, 0, 0);
                acc[2][nt] = __builtin_amdgcn_mfma_f32_16x16x32_f16(F2h.v, bh.v, acc[2][nt], 0, 0, 0);
            }
        }

        // ---- epilogue: residuals, per-pixel gradient dots, reduce, route ----
        float Ap[4];
        #pragma unroll
        for (int rr2 = 0; rr2 < 4; ++rr2) Ap[rr2] = __shfl(A, q*4 + rr2);

        float SA[4], SK[4], ST[4];
        #pragma unroll
        for (int r2 = 0; r2 < 4; ++r2) { SA[r2]=0.f; SK[r2]=0.f; ST[r2]=0.f; }
        #pragma unroll
        for (int nt = 0; nt < 4; ++nt)
            #pragma unroll
            for (int r2 = 0; r2 < 4; ++r2) {
                float Y0 = acc[0][nt][r2], Y1 = acc[1][nt][r2], Y2 = acc[2][nt][r2];
                float rr = fmaf(Ap[r2], Y0, -dcreg[nt][r2]);   // est - dc
                SA[r2] = fmaf(rr, Y0, SA[r2]);
                SK[r2] = fmaf(rr, Y1, SK[r2]);
                ST[r2] = fmaf(rr, Y2, ST[r2]);
            }
        #pragma unroll
        for (int r2 = 0; r2 < 4; ++r2)
            #pragma unroll
            for (int m = 1; m < 16; m <<= 1) {
                SA[r2] += __shfl_xor(SA[r2], m);
                SK[r2] += __shfl_xor(SK[r2], m);
                ST[r2] += __shfl_xor(ST[r2], m);
            }
        // route: pixel p=n lives in group p>>2, slot p&3
        int src = (n >> 2) * 16;
        float GA = 0.f, GK = 0.f, GT = 0.f;
        #pragma unroll
        for (int r2 = 0; r2 < 4; ++r2) {
            float tA = __shfl(SA[r2], src);
            float tK = __shfl(SK[r2], src);
            float tT = __shfl(ST[r2], src);
            if ((n & 3) == r2) { GA = tA; GK = tK; GT = tT; }
        }

        float gA = fmaf(rgA, A  - pA, cdc2 * GA)         + 2.0f * fminf(A,  0.f);
        float gK = fmaf(rgK, K  - pK, cdc2 * A * GK)     + 2.0f * fminf(K,  0.f);
        float gT = fmaf(rgT, T0 - pT, cdc2 * A * K * GT) + 2.0f * fminf(T0, 0.f);
        A  -= 0.1f * gA;
        K  -= 0.1f * gK;
        T0 -= 0.1f * gT;
    }

    if (lane < 16) {
        out[mypix]          = A;
        out[NPIX + mypix]   = K;
        out[2*NPIX + mypix] = T0;
    }
}

// -------------------------------------------------------------- launch ------
extern "C" void kernel_launch(void* const* d_in, const int* in_sizes, int n_in,
                              void* d_out, int out_size, void* d_ws, size_t ws_size,
                              hipStream_t stream) {
    const float* ctc   = (const float*)d_in[0];
    const float* aif   = (const float*)d_in[1];
    const float* timev = (const float*)d_in[2];
    const float* eta   = (const float*)d_in[4];
    const float* lam   = (const float*)d_in[5];
    float* out = (float*)d_out;
    // ws layout: [0..4095]  f32x4 partials[256]
    //            [4096..5119] u32 flags[256]   (poison 0xAA... != MAGIC)
    f32x4*        partials = (f32x4*)d_ws;
    unsigned int* flags    = (unsigned int*)((char*)d_ws + 4096);

    k_all<<<NPIX / 64, 256, 0, stream>>>(ctc, aif, timev, lam, eta,
                                         flags, partials, out);
}

// Round 9
// 117.785 us; speedup vs baseline: 1.6143x; 1.6143x over previous
//
#include <hip/hip_runtime.h>
#include <math.h>

#define T_IN 64
#define NPIX 16384
#define MAX_ITER 10
#define NSLOT 43
#define MAGIC 0x13579BDFu

typedef _Float16 half8_t __attribute__((ext_vector_type(8)));
typedef __fp16   fp16x2  __attribute__((ext_vector_type(2)));
typedef float    f32x4   __attribute__((ext_vector_type(4)));
typedef int      i32x4   __attribute__((ext_vector_type(4)));

union H8 { half8_t v; fp16x2 h2[4]; i32x4 i4; };

__device__ __forceinline__ float rcp_fast(float x) { return __builtin_amdgcn_rcpf(x); }

// ---------------------------------------------------------------- all -------
// Single dispatch, grid 256. __launch_bounds__(256,1): R8's (256,2) capped
// VGPRs at 128 and spilled the 172-reg Breg hoist to scratch (FETCH_SIZE
// 2.3MB -> 201MB). With (256,1) VGPR~220 -> >=1 block/CU -> device capacity
// >= grid -> all blocks dispatch at t=0 -> grid barrier deadlock-free.
__global__ __launch_bounds__(256, 1) void k_all(
        const float* __restrict__ ctc,  const float* __restrict__ aif,
        const float* __restrict__ timev,const float* __restrict__ lam,
        const float* __restrict__ eta,  unsigned int* __restrict__ flags,
        f32x4* __restrict__ partials,   float* __restrict__ out) {
    __shared__ i32x4 Bs[NSLOT * 64];   // 43 KB
    __shared__ float tshs[512];        // 2 KB
    __shared__ float aifos[512];       // 2 KB
    __shared__ float a_s[64], t_s[64];
    __shared__ f32x4 red[4];

    const int tid  = threadIdx.x;
    const int lane = tid & 63;
    const int wid  = tid >> 6;
    const int q = lane >> 4, n = lane & 15;
    const int pixbase = blockIdx.x * 64 + wid * 16;
    const int mypix   = pixbase + n;

    // ---- phase A: local setup ----
    if (tid < 64) { a_s[tid] = aif[tid]; t_s[tid] = timev[tid]; }
    float A  = eta[mypix];
    float K  = eta[NPIX + mypix];
    float T0 = eta[2*NPIX + mypix];
    const float pA = A, pK = K, pT = T0;
    __syncthreads();
    {
        float m5a = 0.2f * (a_s[0]+a_s[1]+a_s[2]+a_s[3]+a_s[4]);
        float t16;
        {   // t_os[16]: x = (16-3.5)/8 = 1.5625
            float xx = 1.5625f; int i0 = (int)xx; float f = xx - (float)i0;
            t16 = t_s[i0]*(1.0f-f) + t_s[i0+1]*f;
        }
        #pragma unroll
        for (int rep = 0; rep < 2; ++rep) {
            int i = tid + 256*rep;
            float x = ((float)i - 3.5f) * 0.125f;
            float ao, to;
            if (x <= 0.0f)       { ao = a_s[0]  - m5a; to = t_s[0];  }
            else if (x >= 63.0f) { ao = a_s[63] - m5a; to = t_s[63]; }
            else {
                int i0 = (int)x; float f = x - (float)i0;
                ao = (a_s[i0]-m5a)*(1.0f-f) + (a_s[i0+1]-m5a)*f;
                to = t_s[i0]*(1.0f-f) + t_s[i0+1]*f;
            }
            aifos[i] = ao;
            tshs[i]  = to - t16;
        }
    }

    // ctc_dc in C-layout registers: dcreg[nt][reg] = dc[p=q*4+reg][d=nt*16+n]
    float dcreg[4][4];
    #pragma unroll
    for (int reg = 0; reg < 4; ++reg) {
        const float* cp = ctc + (pixbase + q*4 + reg) * T_IN;
        float m5 = 0.2f * (cp[0]+cp[1]+cp[2]+cp[3]+cp[4]);
        #pragma unroll
        for (int nt = 0; nt < 4; ++nt) {
            int d = nt*16 + n;
            float cc = cp[d] - m5;
            float cm = cp[(d > 0) ? d-1 : 0] - m5;
            dcreg[nt][reg] = (d == 0) ? cc : (0.4375f*cm + 0.5625f*cc);
        }
    }

    // block partials: C_dc = sum dcreg^2 (each (px,d) once across the wave);
    // C_nn: each pixel appears on 4 lanes (q=0..3) -> sum/4.
    {
        float vs = 0.f;
        #pragma unroll
        for (int nt = 0; nt < 4; ++nt)
            #pragma unroll
            for (int r2 = 0; r2 < 4; ++r2) vs += dcreg[nt][r2]*dcreg[nt][r2];
        f32x4 pv = (f32x4){vs, 0.25f*A*A, 0.25f*K*K, 0.25f*T0*T0};
        #pragma unroll
        for (int m = 1; m < 64; m <<= 1) {
            pv.x += __shfl_xor(pv.x, m); pv.y += __shfl_xor(pv.y, m);
            pv.z += __shfl_xor(pv.z, m); pv.w += __shfl_xor(pv.w, m);
        }
        if (lane == 0) red[wid] = pv;
    }
    __syncthreads();
    if (tid == 0) {
        f32x4 s = red[0] + red[1] + red[2] + red[3];
        partials[blockIdx.x] = s;
        __threadfence();
        __hip_atomic_store(&flags[blockIdx.x], MAGIC, __ATOMIC_RELEASE,
                           __HIP_MEMORY_SCOPE_AGENT);
    }

    // ---- build B tiles in LDS (overlaps barrier skew), RTN ----
    for (int idx = tid; idx < NSLOT * 64; idx += 256) {
        int slot = idx >> 6, l = idx & 63;
        int kt, nt;
        if (slot < 20)      { kt = slot >> 2; nt = slot & 3; }
        else if (slot < 32) { int s = slot - 20; int d3 = s / 3; kt = 5 + d3; nt = 1 + (s - 3*d3); }
        else if (slot < 40) { int s = slot - 32; kt = 9 + (s >> 1); nt = 2 + (s & 1); }
        else                { kt = 13 + (slot - 40); nt = 3; }
        int kbase = 32*kt + 8*(l >> 4);
        int m = 16 + 8 * (16*nt + (l & 15));   // m_d = 16+8d
        H8 bh;
        #pragma unroll
        for (int jj = 0; jj < 4; ++jj) {
            float v[2];
            #pragma unroll
            for (int h = 0; h < 2; ++h) {
                int k  = kbase + 2*jj + h;
                int ai = m - k;
                float s2 = 1.0f / (1.0f + __expf(-500.0f * tshs[k]));
                v[h] = (ai >= 0 && ai < 512) ? s2 * aifos[ai] * 0.125f : 0.0f;
            }
            bh.h2[jj] = (fp16x2){(__fp16)v[0], (__fp16)v[1]};   // RTN
        }
        Bs[idx] = bh.i4;
    }
    __syncthreads();

    // ---- hoist B into registers (iteration-invariant) ----
    i32x4 Breg[NSLOT];
    #pragma unroll
    for (int s = 0; s < NSLOT; ++s) Breg[s] = Bs[s*64 + lane];

    // ---- grid barrier: thread t watches flags[t] ----
    while (__hip_atomic_load(&flags[tid], __ATOMIC_ACQUIRE,
                             __HIP_MEMORY_SCOPE_AGENT) != MAGIC)
        __builtin_amdgcn_s_sleep(2);
    __syncthreads();

    // ---- reduce the 256 partials (4 per lane, then wave shuffle) ----
    f32x4 tot = partials[lane] + partials[64+lane] + partials[128+lane]
              + partials[192+lane];
    #pragma unroll
    for (int m = 1; m < 64; m <<= 1) {
        tot.x += __shfl_xor(tot.x, m); tot.y += __shfl_xor(tot.y, m);
        tot.z += __shfl_xor(tot.z, m); tot.w += __shfl_xor(tot.w, m);
    }
    float spl;
    {
        float xl = lam[0];
        spl = (xl > 0.0f) ? (xl + log1pf(__expf(-xl))) : log1pf(__expf(xl));
    }
    const float cdc2 = 2.0f / tot.x;
    const float rgA  = 2.0f * spl / tot.y;
    const float rgK  = 2.0f * spl / tot.z;
    const float rgT  = 2.0f * spl / tot.w;

    constexpr int NTMIN[16] = {0,0,0,0,0,1,1,1,1,2,2,2,2,3,3,3};
    constexpr int TOFS[16]  = {0,4,8,12,16,20,23,26,29,32,34,36,38,40,41,42};

    #pragma unroll 1
    for (int it = 0; it < MAX_ITER; ++it) {
        f32x4 acc[3][4];
        #pragma unroll
        for (int f = 0; f < 3; ++f)
            #pragma unroll
            for (int t = 0; t < 4; ++t)
                acc[f][t] = (f32x4){0.f, 0.f, 0.f, 0.f};

        float nK = -K;
        float r  = __expf(0.125f * K);     // x ratio per t-step
        #pragma unroll
        for (int kt = 0; kt < 16; ++kt) {
            f32x4 tv0 = *(const f32x4*)&tshs[32*kt + 8*q];
            f32x4 tv1 = *(const f32x4*)&tshs[32*kt + 8*q + 4];
            float d1[8];
            d1[0]=T0-tv0[0]; d1[1]=T0-tv0[1]; d1[2]=T0-tv0[2]; d1[3]=T0-tv0[3];
            d1[4]=T0-tv1[0]; d1[5]=T0-tv1[1]; d1[6]=T0-tv1[2]; d1[7]=T0-tv1[3];
            float x[8];
            if (kt == 0 || kt == 15) {
                bool edge = (kt == 0) ? (q == 0) : (q == 3);  // flat tsh samples
                if (edge) {
                    #pragma unroll
                    for (int j = 0; j < 8; ++j) x[j] = __expf(nK * d1[j]);
                } else {
                    x[0] = __expf(nK * d1[0]);
                    #pragma unroll
                    for (int j = 1; j < 8; ++j) x[j] = x[j-1] * r;
                }
            } else {
                x[0] = __expf(nK * d1[0]);
                #pragma unroll
                for (int j = 1; j < 8; ++j) x[j] = x[j-1] * r;
            }
            H8 F0h, F1h, F2h;
            #pragma unroll
            for (int jj = 0; jj < 4; ++jj) {
                float s1a = rcp_fast(1.0f + x[2*jj]);
                float s1b = rcp_fast(1.0f + x[2*jj+1]);
                fp16x2 sh  = (fp16x2){(__fp16)s1a, (__fp16)s1b};          // RTN
                fp16x2 d1h = __builtin_amdgcn_cvt_pkrtz(d1[2*jj], d1[2*jj+1]);
                fp16x2 eh  = sh - sh*sh;                                  // v_pk f16
                F0h.h2[jj] = sh;
                F1h.h2[jj] = eh * d1h;
                F2h.h2[jj] = eh;
            }
            #pragma unroll
            for (int nt = NTMIN[kt]; nt < 4; ++nt) {
                int slot = TOFS[kt] + nt - NTMIN[kt];
                H8 bh; bh.i4 = Breg[slot];
                acc[0][nt] = __builtin_amdgcn_mfma_f32_16x16x32_f16(F0h.v, bh.v, acc[0][nt], 0, 0, 0);
                acc[1][nt] = __builtin_amdgcn_mfma_f32_16x16x32_f16(F1h.v, bh.v, acc[1][nt], 0, 0, 0);
                acc[2][nt] = __builtin_amdgcn_mfma_f32_16x16x32_f16(F2h.v, bh.v, acc[2][nt], 0, 0, 0);
            }
        }

        // ---- epilogue: residuals, per-pixel gradient dots, reduce, route ----
        float Ap[4];
        #pragma unroll
        for (int rr2 = 0; rr2 < 4; ++rr2) Ap[rr2] = __shfl(A, q*4 + rr2);

        float SA[4], SK[4], ST[4];
        #pragma unroll
        for (int r2 = 0; r2 < 4; ++r2) { SA[r2]=0.f; SK[r2]=0.f; ST[r2]=0.f; }
        #pragma unroll
        for (int nt = 0; nt < 4; ++nt)
            #pragma unroll
            for (int r2 = 0; r2 < 4; ++r2) {
                float Y0 = acc[0][nt][r2], Y1 = acc[1][nt][r2], Y2 = acc[2][nt][r2];
                float rr = fmaf(Ap[r2], Y0, -dcreg[nt][r2]);   // est - dc
                SA[r2] = fmaf(rr, Y0, SA[r2]);
                SK[r2] = fmaf(rr, Y1, SK[r2]);
                ST[r2] = fmaf(rr, Y2, ST[r2]);
            }
        #pragma unroll
        for (int r2 = 0; r2 < 4; ++r2)
            #pragma unroll
            for (int m = 1; m < 16; m <<= 1) {
                SA[r2] += __shfl_xor(SA[r2], m);
                SK[r2] += __shfl_xor(SK[r2], m);
                ST[r2] += __shfl_xor(ST[r2], m);
            }
        // route: pixel p=n lives in group p>>2, slot p&3
        int src = (n >> 2) * 16;
        float GA = 0.f, GK = 0.f, GT = 0.f;
        #pragma unroll
        for (int r2 = 0; r2 < 4; ++r2) {
            float tA = __shfl(SA[r2], src);
            float tK = __shfl(SK[r2], src);
            float tT = __shfl(ST[r2], src);
            if ((n & 3) == r2) { GA = tA; GK = tK; GT = tT; }
        }

        float gA = fmaf(rgA, A  - pA, cdc2 * GA)         + 2.0f * fminf(A,  0.f);
        float gK = fmaf(rgK, K  - pK, cdc2 * A * GK)     + 2.0f * fminf(K,  0.f);
        float gT = fmaf(rgT, T0 - pT, cdc2 * A * K * GT) + 2.0f * fminf(T0, 0.f);
        A  -= 0.1f * gA;
        K  -= 0.1f * gK;
        T0 -= 0.1f * gT;
    }

    if (lane < 16) {
        out[mypix]          = A;
        out[NPIX + mypix]   = K;
        out[2*NPIX + mypix] = T0;
    }
}

// -------------------------------------------------------------- launch ------
extern "C" void kernel_launch(void* const* d_in, const int* in_sizes, int n_in,
                              void* d_out, int out_size, void* d_ws, size_t ws_size,
                              hipStream_t stream) {
    const float* ctc   = (const float*)d_in[0];
    const float* aif   = (const float*)d_in[1];
    const float* timev = (const float*)d_in[2];
    const float* eta   = (const float*)d_in[4];
    const float* lam   = (const float*)d_in[5];
    float* out = (float*)d_out;
    // ws layout: [0..4095]  f32x4 partials[256]
    //            [4096..5119] u32 flags[256]   (poison 0xAA... != MAGIC)
    f32x4*        partials = (f32x4*)d_ws;
    unsigned int* flags    = (unsigned int*)((char*)d_ws + 4096);

    k_all<<<NPIX / 64, 256, 0, stream>>>(ctc, aif, timev, lam, eta,
                                         flags, partials, out);
}